// Round 1
// baseline (143.587 us; speedup 1.0000x reference)
//
#include <hip/hip_runtime.h>
#include <math.h>

// Problem constants
#define Bb 4
#define Cc 64
#define Hh 64
#define Ww 64
#define Ss 20

constexpr int XC = Hh * Ww * Ss;   // 81920  : x channel stride
constexpr int XH = Ww * Ss;        // 1280   : x row stride
constexpr int XW = Ss;             // 20     : x col stride
constexpr int XB = Cc * XC;        // 5242880: x batch stride

// ws layout (floats): [0,576) Weff[tap][c'], [576,585) btap[tap],
//                     [640, 640+327680) Bk[site][t]  (site = (b*H+h)*W+w)

// ---------------------------------------------------------------------------
// Kernel 1: fold the K-branch 1x1 conv into the 3x3 conv.
// Weff[tap][c'] = sum_c w2[0,64+c,tap] * w1[64+c, c']
// btap[tap]     = sum_c w2[0,64+c,tap] * b1[64+c]
// ---------------------------------------------------------------------------
__global__ void ct_fold_weights(const float* __restrict__ w1,
                                const float* __restrict__ b1,
                                const float* __restrict__ w2,
                                float* __restrict__ ws) {
    int tid = threadIdx.x;
    if (tid < 576) {
        int tap = tid >> 6, cp = tid & 63;
        float acc = 0.f;
        #pragma unroll 8
        for (int c = 0; c < 64; ++c)
            acc += w2[(64 + c) * 9 + tap] * w1[(64 + c) * 64 + cp];
        ws[tid] = acc;
    } else if (tid < 585) {
        int tap = tid - 576;
        float acc = 0.f;
        for (int c = 0; c < 64; ++c)
            acc += w2[(64 + c) * 9 + tap] * b1[64 + c];
        ws[576 + tap] = acc;
    }
}

// ---------------------------------------------------------------------------
// Kernel 2: Bk[b,h,w,t] = sum_{taps in-bounds} ( sum_c' Weff[tap][c'] *
//           x[b,c',h+dh-1,w+dw-1,t] + btap[tap] )
// One block per (b,h) row; 320 threads = 64 w * 5 t4 (float4 over t).
// Consecutive tid -> consecutive 16B in x => perfect coalescing.
// XCD swizzle keeps h-neighbors on the same XCD for L2 halo reuse.
// ---------------------------------------------------------------------------
__global__ __launch_bounds__(320) void ct_conv_bk(
        const float* __restrict__ x,
        const float* __restrict__ ws,
        float* __restrict__ bk) {
    __shared__ float weff[576];
    __shared__ float btap[9];
    int tid = threadIdx.x;
    for (int i = tid; i < 576; i += 320) weff[i] = ws[i];
    if (tid < 9) btap[tid] = ws[576 + tid];
    __syncthreads();

    int lin = blockIdx.x;                     // 0..255
    int nl  = (lin & 7) * 32 + (lin >> 3);    // contiguous chunks per XCD
    int b = nl >> 6, h = nl & 63;
    int w = tid / 5, t4 = tid % 5;

    // per-tap bias (only in-bounds taps; conv pads K with zeros, not bias)
    float bsum = 0.f;
    for (int dh = 0; dh < 3; ++dh) {
        int hh = h + dh - 1;
        if (hh < 0 || hh >= Hh) continue;
        for (int dw = 0; dw < 3; ++dw) {
            int ww_ = w + dw - 1;
            if (ww_ < 0 || ww_ >= Ww) continue;
            bsum += btap[dh * 3 + dw];
        }
    }
    float4 acc;
    acc.x = acc.y = acc.z = acc.w = bsum;

    const float* xb = x + b * XB + h * XH + w * XW + t4 * 4;
    for (int c = 0; c < 64; ++c) {
        const float* xc = xb + c * XC;
        #pragma unroll
        for (int dh = 0; dh < 3; ++dh) {
            int hh = h + dh - 1;
            if (hh < 0 || hh >= Hh) continue;
            #pragma unroll
            for (int dw = 0; dw < 3; ++dw) {
                int ww_ = w + dw - 1;
                if (ww_ < 0 || ww_ >= Ww) continue;
                float wv = weff[(dh * 3 + dw) * 64 + c];
                const float4 xv = *reinterpret_cast<const float4*>(
                    xc + (dh - 1) * XH + (dw - 1) * XW);
                acc.x = fmaf(wv, xv.x, acc.x);
                acc.y = fmaf(wv, xv.y, acc.y);
                acc.z = fmaf(wv, xv.z, acc.z);
                acc.w = fmaf(wv, xv.w, acc.w);
            }
        }
    }
    int site = nl * 64 + w;
    *reinterpret_cast<float4*>(bk + site * 20 + t4 * 4) = acc;
}

// ---------------------------------------------------------------------------
// Kernel 3: per site (b,h,w): p = softmax_t(Bk), xbar[c] = sum_t p[t]*x[c,t],
//           R[c] = b1v[c] + sum_c' w1v[c,c']*xbar[c'], out[c,:,s] = R[c].
// 256 threads = 4 sites * 64 lanes; wave <-> site (no cross-wave softmax).
// w1v staged transposed in LDS with +1 pad => conflict-free reads.
// ---------------------------------------------------------------------------
__global__ __launch_bounds__(256) void ct_attn_out(
        const float* __restrict__ x,
        const float* __restrict__ w1,
        const float* __restrict__ b1,
        const float* __restrict__ bk,
        float* __restrict__ out) {
    __shared__ float w1t[64 * 65];   // w1t[cp*65 + c] = w1v[c][cp]
    __shared__ float xsh[4][64];
    int tid = threadIdx.x;
    #pragma unroll
    for (int k = 0; k < 16; ++k) {
        int j = tid + k * 256;       // 0..4095, coalesced global read
        int r = j >> 6, q = j & 63;
        w1t[q * 65 + r] = w1[8192 + j];   // w1v row r, col q
    }

    int ls = tid >> 6, c = tid & 63;
    int site = blockIdx.x * 4 + ls;       // 0..16383
    int b = site >> 12, hw = site & 4095;

    // softmax over t of Bk (all lanes of the wave read the same 20 floats)
    const float* bkp = bk + site * 20;
    float p[20];
    #pragma unroll
    for (int i = 0; i < 5; ++i) {
        float4 t = reinterpret_cast<const float4*>(bkp)[i];
        p[4 * i] = t.x; p[4 * i + 1] = t.y; p[4 * i + 2] = t.z; p[4 * i + 3] = t.w;
    }
    float m = p[0];
    #pragma unroll
    for (int i = 1; i < 20; ++i) m = fmaxf(m, p[i]);
    float ssum = 0.f;
    #pragma unroll
    for (int i = 0; i < 20; ++i) { p[i] = __expf(p[i] - m); ssum += p[i]; }

    // xbar[c] = (1/ssum) * sum_t e[t] * x[b,c,h,w,t]
    const float* xp = x + (b * 64 + c) * XC + hw * 20;
    float xbv = 0.f;
    #pragma unroll
    for (int i = 0; i < 5; ++i) {
        float4 xv = reinterpret_cast<const float4*>(xp)[i];
        xbv = fmaf(p[4 * i],     xv.x, xbv);
        xbv = fmaf(p[4 * i + 1], xv.y, xbv);
        xbv = fmaf(p[4 * i + 2], xv.z, xbv);
        xbv = fmaf(p[4 * i + 3], xv.w, xbv);
    }
    xsh[ls][c] = xbv / ssum;
    __syncthreads();

    // R[c] = b1v[c] + sum_cp w1v[c][cp] * xbar[cp]
    float R = b1[128 + c];
    #pragma unroll 8
    for (int cp = 0; cp < 64; ++cp)
        R = fmaf(w1t[cp * 65 + c], xsh[ls][cp], R);

    // broadcast along s
    float* op = out + (b * 64 + c) * XC + hw * 20;
    float4 rv = make_float4(R, R, R, R);
    #pragma unroll
    for (int s4 = 0; s4 < 5; ++s4)
        reinterpret_cast<float4*>(op)[s4] = rv;
}

extern "C" void kernel_launch(void* const* d_in, const int* in_sizes, int n_in,
                              void* d_out, int out_size, void* d_ws, size_t ws_size,
                              hipStream_t stream) {
    const float* x  = (const float*)d_in[0];
    const float* w1 = (const float*)d_in[1];
    const float* b1 = (const float*)d_in[2];
    const float* w2 = (const float*)d_in[3];
    // d_in[4] (b2) is mathematically dead: it cancels in the softmax over t.
    float* ws    = (float*)d_ws;
    float* bkbuf = ws + 640;
    float* out   = (float*)d_out;

    ct_fold_weights<<<1, 640, 0, stream>>>(w1, b1, w2, ws);
    ct_conv_bk<<<256, 320, 0, stream>>>(x, ws, bkbuf);
    ct_attn_out<<<4096, 256, 0, stream>>>(x, w1, b1, bkbuf, out);
}

// Round 3
// 88.990 us; speedup vs baseline: 1.6135x; 1.6135x over previous
//
#include <hip/hip_runtime.h>
#include <math.h>

// Problem constants
#define Bb 4
#define Cc 64
#define Hh 64
#define Ww 64
#define Ss 20

constexpr int XC = Hh * Ww * Ss;   // 81920  : x channel stride
constexpr int XH = Ww * Ss;        // 1280   : x row stride
constexpr int XW = Ss;             // 20     : x col stride
constexpr int XB = Cc * XC;        // 5242880: x batch stride
constexpr int NSITE = Bb * Hh * Ww;    // 16384
constexpr int BKPLANE = NSITE * Ss;    // 327680 floats per partial plane

// ws layout (floats): [0,576) Weff[tap][c'], [576,585) btap[tap],
//                     [640, 640 + NPART*BKPLANE) partial Bk planes

// ---------------------------------------------------------------------------
// Kernel 1: fold the K-branch 1x1 conv into the 3x3 conv.
// Weff[tap][c'] = sum_c w2[0,64+c,tap] * w1[64+c, c']
// btap[tap]     = sum_c w2[0,64+c,tap] * b1[64+c]
// ---------------------------------------------------------------------------
__global__ void ct_fold_weights(const float* __restrict__ w1,
                                const float* __restrict__ b1,
                                const float* __restrict__ w2,
                                float* __restrict__ ws) {
    int tid = threadIdx.x;
    if (tid < 576) {
        int tap = tid >> 6, cp = tid & 63;
        float acc = 0.f;
        #pragma unroll 8
        for (int c = 0; c < 64; ++c)
            acc += w2[(64 + c) * 9 + tap] * w1[(64 + c) * 64 + cp];
        ws[tid] = acc;
    } else if (tid < 585) {
        int tap = tid - 576;
        float acc = 0.f;
        for (int c = 0; c < 64; ++c)
            acc += w2[(64 + c) * 9 + tap] * b1[64 + c];
        ws[576 + tap] = acc;
    }
}

// ---------------------------------------------------------------------------
// Kernel 2: partial Bk over a channel slice.
// grid = 256*NPART blocks, 320 threads = 64 w * 5 t4 (float4 over t).
// Branch-free taps: OOB tap addresses clamped in-bounds, weight zeroed via
// vmask -> straight-line 9-load/36-FMA body the compiler can pipeline.
// XCD swizzle: contiguous (part, b, h) chunk per XCD for halo L2 reuse.
// ---------------------------------------------------------------------------
template<int NPART>
__global__ __launch_bounds__(320) void ct_conv_bk(
        const float* __restrict__ x,
        const float* __restrict__ ws,
        float* __restrict__ bk) {
    __shared__ float weff[576];
    __shared__ float btap[9];
    int tid = threadIdx.x;
    for (int i = tid; i < 576; i += 320) weff[i] = ws[i];
    if (tid < 9) btap[tid] = ws[576 + tid];
    __syncthreads();

    constexpr int NCP = 64 / NPART;          // channels per block
    constexpr int CHUNK = 256 * NPART / 8;   // blocks per XCD
    int g = (blockIdx.x & 7) * CHUNK + (blockIdx.x >> 3);
    int part = g >> 8;                        // 0..NPART-1
    int nl = g & 255;
    int b = nl >> 6, h = nl & 63;
    int w = tid / 5, t4 = tid % 5;

    // clamped tap offsets + 0/1 validity masks (branch-free inner loop)
    float vmask[9];
    int off[9];
    #pragma unroll
    for (int dh = 0; dh < 3; ++dh) {
        int hh = h + dh - 1;
        float hv = (hh >= 0 && hh < Hh) ? 1.f : 0.f;
        int hc = hh < 0 ? 0 : (hh > Hh - 1 ? Hh - 1 : hh);
        #pragma unroll
        for (int dw = 0; dw < 3; ++dw) {
            int wc = w + dw - 1;
            float wvd = (wc >= 0 && wc < Ww) ? 1.f : 0.f;
            int wcl = wc < 0 ? 0 : (wc > Ww - 1 ? Ww - 1 : wc);
            vmask[dh * 3 + dw] = hv * wvd;
            off[dh * 3 + dw] = hc * XH + wcl * XW;
        }
    }

    // per-tap bias only in partial plane 0
    float bsum = 0.f;
    if (part == 0) {
        #pragma unroll
        for (int tap = 0; tap < 9; ++tap) bsum += btap[tap] * vmask[tap];
    }
    float4 acc = make_float4(bsum, bsum, bsum, bsum);

    const float* xb = x + b * XB + part * NCP * XC + t4 * 4;
    #pragma unroll 2
    for (int c = 0; c < NCP; ++c) {
        const float* xc = xb + c * XC;
        #pragma unroll
        for (int tap = 0; tap < 9; ++tap) {
            float wv = weff[tap * 64 + part * NCP + c] * vmask[tap];
            const float4 xv = *reinterpret_cast<const float4*>(xc + off[tap]);
            acc.x = fmaf(wv, xv.x, acc.x);
            acc.y = fmaf(wv, xv.y, acc.y);
            acc.z = fmaf(wv, xv.z, acc.z);
            acc.w = fmaf(wv, xv.w, acc.w);
        }
    }
    int site = nl * 64 + w;
    *reinterpret_cast<float4*>(bk + part * BKPLANE + site * 20 + t4 * 4) = acc;
}

// ---------------------------------------------------------------------------
// Kernel 3: block = 16 consecutive sites, 256 threads.
// si = tid&15 (site), cg = tid>>4 (channel group); each thread owns
// channels c = cg*4+k, k=0..3  ->  16 sites * 64 channels fully covered.
// 16 consecutive-si lanes read/write 1280 contiguous bytes (coalesced).
// softmax_t(sum of Bk partials) once per site into LDS; then
// xbar[si][c] = sum_t p*x; R[c] = b1v[c] + sum_cp w1v[c,cp]*xbar[cp];
// out[c,site,s] = R broadcast along s. LDS strides 65 => conflict-free.
// ---------------------------------------------------------------------------
template<int NPART>
__global__ __launch_bounds__(256) void ct_attn_out(
        const float* __restrict__ x,
        const float* __restrict__ w1,
        const float* __restrict__ b1,
        const float* __restrict__ bk,
        float* __restrict__ out) {
    __shared__ float w1t[64 * 65];   // w1t[cp*65 + c] = w1v[c][cp]
    __shared__ float psm[16][20];
    __shared__ float xsh[16][65];
    int tid = threadIdx.x;
    #pragma unroll
    for (int k = 0; k < 16; ++k) {
        int j = tid + k * 256;            // coalesced global read
        int r = j >> 6, q = j & 63;
        w1t[q * 65 + r] = w1[8192 + j];   // w1v row r, col q
    }

    int site0 = blockIdx.x * 16;
    if (tid < 16) {                       // one softmax per site
        int site = site0 + tid;
        float p[20];
        #pragma unroll
        for (int i = 0; i < 20; ++i) {
            float v = 0.f;
            #pragma unroll
            for (int pt = 0; pt < NPART; ++pt)
                v += bk[pt * BKPLANE + site * 20 + i];
            p[i] = v;
        }
        float m = p[0];
        #pragma unroll
        for (int i = 1; i < 20; ++i) m = fmaxf(m, p[i]);
        float ssum = 0.f;
        #pragma unroll
        for (int i = 0; i < 20; ++i) { p[i] = __expf(p[i] - m); ssum += p[i]; }
        float inv = 1.f / ssum;
        #pragma unroll
        for (int i = 0; i < 20; ++i) psm[tid][i] = p[i] * inv;
    }
    __syncthreads();

    int si = tid & 15, cg = tid >> 4;     // cg in 0..15
    int site = site0 + si;
    int b = site >> 12, hw = site & 4095;

    // xbar for this thread's 4 channels
    #pragma unroll
    for (int k = 0; k < 4; ++k) {
        int c = cg * 4 + k;
        const float* xp = x + (b * 64 + c) * XC + hw * 20;
        float xbv = 0.f;
        #pragma unroll
        for (int i = 0; i < 5; ++i) {
            float4 xv = reinterpret_cast<const float4*>(xp)[i];
            xbv = fmaf(psm[si][4 * i],     xv.x, xbv);
            xbv = fmaf(psm[si][4 * i + 1], xv.y, xbv);
            xbv = fmaf(psm[si][4 * i + 2], xv.z, xbv);
            xbv = fmaf(psm[si][4 * i + 3], xv.w, xbv);
        }
        xsh[si][c] = xbv;
    }
    __syncthreads();

    // R[c] = b1v[c] + sum_cp w1v[c][cp] * xbar[cp]; broadcast along s
    #pragma unroll
    for (int k = 0; k < 4; ++k) {
        int c = cg * 4 + k;
        float R = b1[128 + c];
        #pragma unroll 8
        for (int cp = 0; cp < 64; ++cp)
            R = fmaf(w1t[cp * 65 + c], xsh[si][cp], R);
        float* op = out + (b * 64 + c) * XC + hw * 20;
        float4 rv = make_float4(R, R, R, R);
        #pragma unroll
        for (int s4 = 0; s4 < 5; ++s4)
            reinterpret_cast<float4*>(op)[s4] = rv;
    }
}

extern "C" void kernel_launch(void* const* d_in, const int* in_sizes, int n_in,
                              void* d_out, int out_size, void* d_ws, size_t ws_size,
                              hipStream_t stream) {
    const float* x  = (const float*)d_in[0];
    const float* w1 = (const float*)d_in[1];
    const float* b1 = (const float*)d_in[2];
    const float* w2 = (const float*)d_in[3];
    // d_in[4] (b2) is mathematically dead: it cancels in the softmax over t.
    float* ws    = (float*)d_ws;
    float* bkbuf = ws + 640;
    float* out   = (float*)d_out;

    ct_fold_weights<<<1, 640, 0, stream>>>(w1, b1, w2, ws);

    size_t need4 = (size_t)(640 + 4 * BKPLANE) * sizeof(float);
    if (ws_size >= need4) {
        ct_conv_bk<4><<<1024, 320, 0, stream>>>(x, ws, bkbuf);
        ct_attn_out<4><<<1024, 256, 0, stream>>>(x, w1, b1, bkbuf, out);
    } else {
        ct_conv_bk<1><<<256, 320, 0, stream>>>(x, ws, bkbuf);
        ct_attn_out<1><<<1024, 256, 0, stream>>>(x, w1, b1, bkbuf, out);
    }
}

// Round 4
// 80.998 us; speedup vs baseline: 1.7727x; 1.0987x over previous
//
#include <hip/hip_runtime.h>
#include <math.h>

// Problem constants
#define Bb 4
#define Cc 64
#define Hh 64
#define Ww 64
#define Ss 20

constexpr int XC = Hh * Ww * Ss;   // 81920  : x channel stride
constexpr int XH = Ww * Ss;        // 1280   : x row stride
constexpr int XW = Ss;             // 20     : x col stride
constexpr int XB = Cc * XC;        // 5242880: x batch stride
constexpr int NSITE = Bb * Hh * Ww;    // 16384
constexpr int BKPLANE = NSITE * Ss;    // 327680 floats per partial plane

// ws layout (floats): [0,576) Weff[tap][c'], [576,585) btap[tap],
//                     [640, 640 + NPART*BKPLANE) partial Bk planes

// ---------------------------------------------------------------------------
// Kernel 1: fold the K-branch 1x1 conv into the 3x3 conv.
// Weff[tap][c'] = sum_c w2[0,64+c,tap] * w1[64+c, c']
// btap[tap]     = sum_c w2[0,64+c,tap] * b1[64+c]
// ---------------------------------------------------------------------------
__global__ void ct_fold_weights(const float* __restrict__ w1,
                                const float* __restrict__ b1,
                                const float* __restrict__ w2,
                                float* __restrict__ ws) {
    int tid = threadIdx.x;
    if (tid < 576) {
        int tap = tid >> 6, cp = tid & 63;
        float acc = 0.f;
        #pragma unroll 8
        for (int c = 0; c < 64; ++c)
            acc += w2[(64 + c) * 9 + tap] * w1[(64 + c) * 64 + cp];
        ws[tid] = acc;
    } else if (tid < 585) {
        int tap = tid - 576;
        float acc = 0.f;
        for (int c = 0; c < 64; ++c)
            acc += w2[(64 + c) * 9 + tap] * b1[64 + c];
        ws[576 + tap] = acc;
    }
}

// ---------------------------------------------------------------------------
// Kernel 2: partial Bk over a channel slice.
// grid = 256*NPART blocks, 320 threads = 64 w * 5 t4 (float4 over t).
// Branch-free taps: OOB tap addresses clamped in-bounds, weight zeroed via
// vmask -> straight-line 9-load/36-FMA body the compiler can pipeline.
// XCD swizzle: each XCD owns contiguous (part,b,h) chunk for halo L2 reuse.
// ---------------------------------------------------------------------------
template<int NPART>
__global__ __launch_bounds__(320) void ct_conv_bk(
        const float* __restrict__ x,
        const float* __restrict__ ws,
        float* __restrict__ bk) {
    __shared__ float weff[576];
    __shared__ float btap[9];
    int tid = threadIdx.x;
    for (int i = tid; i < 576; i += 320) weff[i] = ws[i];
    if (tid < 9) btap[tid] = ws[576 + tid];
    __syncthreads();

    constexpr int NCP = 64 / NPART;          // channels per block
    constexpr int CHUNK = 256 * NPART / 8;   // blocks per XCD
    int g = (blockIdx.x & 7) * CHUNK + (blockIdx.x >> 3);
    int part = g >> 8;                        // 0..NPART-1
    int nl = g & 255;
    int b = nl >> 6, h = nl & 63;
    int w = tid / 5, t4 = tid % 5;

    // clamped tap offsets + 0/1 validity masks (branch-free inner loop)
    float vmask[9];
    int off[9];
    #pragma unroll
    for (int dh = 0; dh < 3; ++dh) {
        int hh = h + dh - 1;
        float hv = (hh >= 0 && hh < Hh) ? 1.f : 0.f;
        int hc = hh < 0 ? 0 : (hh > Hh - 1 ? Hh - 1 : hh);
        #pragma unroll
        for (int dw = 0; dw < 3; ++dw) {
            int wc = w + dw - 1;
            float wvd = (wc >= 0 && wc < Ww) ? 1.f : 0.f;
            int wcl = wc < 0 ? 0 : (wc > Ww - 1 ? Ww - 1 : wc);
            vmask[dh * 3 + dw] = hv * wvd;
            off[dh * 3 + dw] = hc * XH + wcl * XW;
        }
    }

    // per-tap bias only in partial plane 0
    float bsum = 0.f;
    if (part == 0) {
        #pragma unroll
        for (int tap = 0; tap < 9; ++tap) bsum += btap[tap] * vmask[tap];
    }
    float4 acc = make_float4(bsum, bsum, bsum, bsum);

    const float* xb = x + b * XB + part * NCP * XC + t4 * 4;
    #pragma unroll 2
    for (int c = 0; c < NCP; ++c) {
        const float* xc = xb + c * XC;
        #pragma unroll
        for (int tap = 0; tap < 9; ++tap) {
            float wv = weff[tap * 64 + part * NCP + c] * vmask[tap];
            const float4 xv = *reinterpret_cast<const float4*>(xc + off[tap]);
            acc.x = fmaf(wv, xv.x, acc.x);
            acc.y = fmaf(wv, xv.y, acc.y);
            acc.z = fmaf(wv, xv.z, acc.z);
            acc.w = fmaf(wv, xv.w, acc.w);
        }
    }
    int site = nl * 64 + w;
    *reinterpret_cast<float4*>(bk + part * BKPLANE + site * 20 + t4 * 4) = acc;
}

// ---------------------------------------------------------------------------
// Kernel 3: block = 8 consecutive sites, 256 threads, grid 2048
// (8 blocks/CU x 4 waves = occupancy cap). si = tid&7, cg = tid>>3 in [0,32);
// each thread owns channels c = cg*2+k, k=0..1 -> 8 sites * 64 ch covered.
// Bk partial-sum parallelized over 160 threads; softmax by 8 threads in LDS.
// xbar[si][c] = sum_t p*x; R[c] = b1v[c] + sum_cp w1v[c,cp]*xbar[cp];
// out[c,site,s] = R broadcast along s. LDS strides 65 => conflict-free.
// ---------------------------------------------------------------------------
template<int NPART>
__global__ __launch_bounds__(256) void ct_attn_out(
        const float* __restrict__ x,
        const float* __restrict__ w1,
        const float* __restrict__ b1,
        const float* __restrict__ bk,
        float* __restrict__ out) {
    __shared__ float w1t[64 * 65];   // w1t[cp*65 + c] = w1v[c][cp]
    __shared__ float psm[8][20];
    __shared__ float xsh[8][65];
    int tid = threadIdx.x;
    #pragma unroll
    for (int k = 0; k < 16; ++k) {
        int j = tid + k * 256;            // coalesced global read
        int r = j >> 6, q = j & 63;
        w1t[q * 65 + r] = w1[8192 + j];   // w1v row r, col q
    }

    int site0 = blockIdx.x * 8;

    // phase A: sum Bk partials, one (site,t) per thread (coalesced per plane)
    if (tid < 160) {
        int si = tid / 20, i = tid % 20;
        float v = 0.f;
        #pragma unroll
        for (int pt = 0; pt < NPART; ++pt)
            v += bk[pt * BKPLANE + (site0 + si) * 20 + i];
        psm[si][i] = v;
    }
    __syncthreads();

    // phase B: softmax per site
    if (tid < 8) {
        float p[20];
        #pragma unroll
        for (int i = 0; i < 20; ++i) p[i] = psm[tid][i];
        float m = p[0];
        #pragma unroll
        for (int i = 1; i < 20; ++i) m = fmaxf(m, p[i]);
        float ssum = 0.f;
        #pragma unroll
        for (int i = 0; i < 20; ++i) { p[i] = __expf(p[i] - m); ssum += p[i]; }
        float inv = 1.f / ssum;
        #pragma unroll
        for (int i = 0; i < 20; ++i) psm[tid][i] = p[i] * inv;
    }
    __syncthreads();

    int si = tid & 7, cg = tid >> 3;      // cg in 0..31
    int site = site0 + si;
    int b = site >> 12, hw = site & 4095;

    // xbar for this thread's 2 channels
    #pragma unroll
    for (int k = 0; k < 2; ++k) {
        int c = cg * 2 + k;
        const float* xp = x + (b * 64 + c) * XC + hw * 20;
        float xbv = 0.f;
        #pragma unroll
        for (int i = 0; i < 5; ++i) {
            float4 xv = reinterpret_cast<const float4*>(xp)[i];
            xbv = fmaf(psm[si][4 * i],     xv.x, xbv);
            xbv = fmaf(psm[si][4 * i + 1], xv.y, xbv);
            xbv = fmaf(psm[si][4 * i + 2], xv.z, xbv);
            xbv = fmaf(psm[si][4 * i + 3], xv.w, xbv);
        }
        xsh[si][c] = xbv;
    }
    __syncthreads();

    // R[c] = b1v[c] + sum_cp w1v[c][cp] * xbar[cp]; broadcast along s
    #pragma unroll
    for (int k = 0; k < 2; ++k) {
        int c = cg * 2 + k;
        float R = b1[128 + c];
        #pragma unroll 8
        for (int cp = 0; cp < 64; ++cp)
            R = fmaf(w1t[cp * 65 + c], xsh[si][cp], R);
        float* op = out + (b * 64 + c) * XC + hw * 20;
        float4 rv = make_float4(R, R, R, R);
        #pragma unroll
        for (int s4 = 0; s4 < 5; ++s4)
            reinterpret_cast<float4*>(op)[s4] = rv;
    }
}

extern "C" void kernel_launch(void* const* d_in, const int* in_sizes, int n_in,
                              void* d_out, int out_size, void* d_ws, size_t ws_size,
                              hipStream_t stream) {
    const float* x  = (const float*)d_in[0];
    const float* w1 = (const float*)d_in[1];
    const float* b1 = (const float*)d_in[2];
    const float* w2 = (const float*)d_in[3];
    // d_in[4] (b2) is mathematically dead: it cancels in the softmax over t.
    float* ws    = (float*)d_ws;
    float* bkbuf = ws + 640;
    float* out   = (float*)d_out;

    ct_fold_weights<<<1, 640, 0, stream>>>(w1, b1, w2, ws);

    size_t need8 = (size_t)(640 + 8 * BKPLANE) * sizeof(float);
    size_t need4 = (size_t)(640 + 4 * BKPLANE) * sizeof(float);
    if (ws_size >= need8) {
        ct_conv_bk<8><<<2048, 320, 0, stream>>>(x, ws, bkbuf);
        ct_attn_out<8><<<2048, 256, 0, stream>>>(x, w1, b1, bkbuf, out);
    } else if (ws_size >= need4) {
        ct_conv_bk<4><<<1024, 320, 0, stream>>>(x, ws, bkbuf);
        ct_attn_out<4><<<2048, 256, 0, stream>>>(x, w1, b1, bkbuf, out);
    } else {
        ct_conv_bk<1><<<256, 320, 0, stream>>>(x, ws, bkbuf);
        ct_attn_out<1><<<2048, 256, 0, stream>>>(x, w1, b1, bkbuf, out);
    }
}

// Round 5
// 73.805 us; speedup vs baseline: 1.9455x; 1.0975x over previous
//
#include <hip/hip_runtime.h>
#include <math.h>

// Problem constants
#define Bb 4
#define Cc 64
#define Hh 64
#define Ww 64
#define Ss 20

constexpr int XC = Hh * Ww * Ss;   // 81920  : x channel stride (floats)
constexpr int XH = Ww * Ss;        // 1280   : x row stride
constexpr int XW = Ss;             // 20     : x col stride
constexpr int XB = Cc * XC;        // 5242880: x batch stride
constexpr int NSITE = Bb * Hh * Ww;    // 16384
constexpr int BKPLANE = NSITE * Ss;    // 327680 floats per partial plane

// ws layout (floats): [0,576) Weff[tap][c'], [576,585) btap[tap],
//                     [640, 640 + NPART*BKPLANE) partial Bk planes

// ---------------------------------------------------------------------------
// Kernel 1: fold the K-branch 1x1 conv into the 3x3 conv.
// Weff[tap][c'] = sum_c w2[0,64+c,tap] * w1[64+c, c']
// btap[tap]     = sum_c w2[0,64+c,tap] * b1[64+c]
// ---------------------------------------------------------------------------
__global__ void ct_fold_weights(const float* __restrict__ w1,
                                const float* __restrict__ b1,
                                const float* __restrict__ w2,
                                float* __restrict__ ws) {
    int tid = threadIdx.x;
    if (tid < 576) {
        int tap = tid >> 6, cp = tid & 63;
        float acc = 0.f;
        #pragma unroll 8
        for (int c = 0; c < 64; ++c)
            acc += w2[(64 + c) * 9 + tap] * w1[(64 + c) * 64 + cp];
        ws[tid] = acc;
    } else if (tid < 585) {
        int tap = tid - 576;
        float acc = 0.f;
        for (int c = 0; c < 64; ++c)
            acc += w2[(64 + c) * 9 + tap] * b1[64 + c];
        ws[576 + tap] = acc;
    }
}

// ---------------------------------------------------------------------------
// Kernel 2 (scatter version): partial Bk over a channel slice, h-tiled.
// Block = (part, b, 4-row h-tile); threads = 64 w * 5 t4 = 320.
// Stream x rows hr = h0-1 .. h0+4; each row is loaded ONCE (NCP x 3 w-shifted
// float4; w+-1 overlap absorbed by L1) and scatter-accumulated into 3 rotating
// register ring accumulators (output rows hr-1, hr, hr+1). A ring slot
// completes after its 3rd contribution -> one coalesced float4 store.
// All ring/array indices are compile-time (full unroll). Logical L2 traffic
// drops 9x -> 1.5x (h-tile halo only). Weights in LDS (broadcast reads).
// ---------------------------------------------------------------------------
template<int NCP>
__global__ __launch_bounds__(320) void ct_conv_scatter(
        const float* __restrict__ x,
        const float* __restrict__ ws,
        float* __restrict__ bk) {
    constexpr int NPART = 64 / NCP;
    constexpr int HT = 4;                    // output rows per block
    constexpr int TOTAL = 4 * NPART * 16;    // grid size
    __shared__ float wsl[9 * NCP];
    __shared__ float bt[9];
    int tid = threadIdx.x;

    // XCD swizzle: h-tiles of the same (part,b) column stay on one XCD.
    int g = (blockIdx.x & 7) * (TOTAL / 8) + (blockIdx.x >> 3);
    int hc = g & 15; g >>= 4;
    int b = g & 3;
    int part = g >> 2;

    if (tid < 9 * NCP)
        wsl[tid] = ws[(tid / NCP) * 64 + part * NCP + (tid % NCP)];
    if (tid < 9) bt[tid] = ws[576 + tid];
    __syncthreads();

    int w = tid / 5, t4 = tid % 5;
    int h0 = hc * HT;
    float m0 = (w == 0)  ? 0.f : 1.f;        // dw=0 reads w-1
    float m2 = (w == 63) ? 0.f : 1.f;        // dw=2 reads w+1
    int wm1 = (w == 0) ? 0 : w - 1;
    int wp1 = (w == 63) ? 63 : w + 1;
    int cw0 = wm1 * XW, cw1 = w * XW, cw2 = wp1 * XW;

    // per-weight-row bias sums (w-edge masked); rows gated per output below
    float bw0 = bt[0] * m0 + bt[1] + bt[2] * m2;
    float bw1 = bt[3] * m0 + bt[4] + bt[5] * m2;
    float bw2 = bt[6] * m0 + bt[7] + bt[8] * m2;
    bool bias_on = (part == 0);

    const float* xbase = x + b * XB + part * NCP * XC + t4 * 4;
    float* bkp = bk + part * BKPLANE;

    float4 ring[3];

    #pragma unroll
    for (int k = 0; k < HT + 2; ++k) {
        // init ring slot for output offset k (output row h0+k)
        if (k < HT) {
            float bs = 0.f;
            if (bias_on) {
                int o = h0 + k;
                bs = (o >= 1 ? bw0 : 0.f) + bw1 + (o + 1 < 64 ? bw2 : 0.f);
            }
            ring[k % 3] = make_float4(bs, bs, bs, bs);
        }

        // load x row hr (zeros if out of bounds; wave-uniform branch)
        int hr = h0 - 1 + k;
        float4 xv[NCP][3];
        if (hr >= 0 && hr < 64) {
            #pragma unroll
            for (int c = 0; c < NCP; ++c) {
                const float* xr = xbase + c * XC + hr * XH;
                xv[c][0] = *reinterpret_cast<const float4*>(xr + cw0);
                xv[c][1] = *reinterpret_cast<const float4*>(xr + cw1);
                xv[c][2] = *reinterpret_cast<const float4*>(xr + cw2);
                xv[c][0].x *= m0; xv[c][0].y *= m0;
                xv[c][0].z *= m0; xv[c][0].w *= m0;
                xv[c][2].x *= m2; xv[c][2].y *= m2;
                xv[c][2].z *= m2; xv[c][2].w *= m2;
            }
        } else {
            #pragma unroll
            for (int c = 0; c < NCP; ++c)
                #pragma unroll
                for (int dw = 0; dw < 3; ++dw)
                    xv[c][dw] = make_float4(0.f, 0.f, 0.f, 0.f);
        }

        // scatter: x row hr -> output offsets k-dh with weight row dh
        #pragma unroll
        for (int dh = 0; dh < 3; ++dh) {
            constexpr int dummy = 0; (void)dummy;
            int off = k - dh;
            if (off < 0 || off >= HT) continue;   // folds at compile time
            int s = off % 3;
            #pragma unroll
            for (int c = 0; c < NCP; ++c) {
                #pragma unroll
                for (int dw = 0; dw < 3; ++dw) {
                    float wv = wsl[(dh * 3 + dw) * NCP + c];
                    ring[s].x = fmaf(wv, xv[c][dw].x, ring[s].x);
                    ring[s].y = fmaf(wv, xv[c][dw].y, ring[s].y);
                    ring[s].z = fmaf(wv, xv[c][dw].z, ring[s].z);
                    ring[s].w = fmaf(wv, xv[c][dw].w, ring[s].w);
                }
            }
        }

        // output offset k-2 is complete -> store
        if (k >= 2) {
            int o = h0 + k - 2;
            int site = (b * 64 + o) * 64 + w;
            *reinterpret_cast<float4*>(bkp + site * 20 + t4 * 4) = ring[(k - 2) % 3];
        }
    }
}

// ---------------------------------------------------------------------------
// Kernel 2 fallback (gather, NPART=4) — known-good from round 3.
// ---------------------------------------------------------------------------
template<int NPART>
__global__ __launch_bounds__(320) void ct_conv_bk(
        const float* __restrict__ x,
        const float* __restrict__ ws,
        float* __restrict__ bk) {
    __shared__ float weff[576];
    __shared__ float btap[9];
    int tid = threadIdx.x;
    for (int i = tid; i < 576; i += 320) weff[i] = ws[i];
    if (tid < 9) btap[tid] = ws[576 + tid];
    __syncthreads();

    constexpr int NCP = 64 / NPART;
    constexpr int CHUNK = 256 * NPART / 8;
    int g = (blockIdx.x & 7) * CHUNK + (blockIdx.x >> 3);
    int part = g >> 8;
    int nl = g & 255;
    int b = nl >> 6, h = nl & 63;
    int w = tid / 5, t4 = tid % 5;

    float vmask[9];
    int off[9];
    #pragma unroll
    for (int dh = 0; dh < 3; ++dh) {
        int hh = h + dh - 1;
        float hv = (hh >= 0 && hh < Hh) ? 1.f : 0.f;
        int hc = hh < 0 ? 0 : (hh > Hh - 1 ? Hh - 1 : hh);
        #pragma unroll
        for (int dw = 0; dw < 3; ++dw) {
            int wc = w + dw - 1;
            float wvd = (wc >= 0 && wc < Ww) ? 1.f : 0.f;
            int wcl = wc < 0 ? 0 : (wc > Ww - 1 ? Ww - 1 : wc);
            vmask[dh * 3 + dw] = hv * wvd;
            off[dh * 3 + dw] = hc * XH + wcl * XW;
        }
    }

    float bsum = 0.f;
    if (part == 0) {
        #pragma unroll
        for (int tap = 0; tap < 9; ++tap) bsum += btap[tap] * vmask[tap];
    }
    float4 acc = make_float4(bsum, bsum, bsum, bsum);

    const float* xb = x + b * XB + part * NCP * XC + t4 * 4;
    #pragma unroll 2
    for (int c = 0; c < NCP; ++c) {
        const float* xc = xb + c * XC;
        #pragma unroll
        for (int tap = 0; tap < 9; ++tap) {
            float wv = weff[tap * 64 + part * NCP + c] * vmask[tap];
            const float4 xv = *reinterpret_cast<const float4*>(xc + off[tap]);
            acc.x = fmaf(wv, xv.x, acc.x);
            acc.y = fmaf(wv, xv.y, acc.y);
            acc.z = fmaf(wv, xv.z, acc.z);
            acc.w = fmaf(wv, xv.w, acc.w);
        }
    }
    int site = nl * 64 + w;
    *reinterpret_cast<float4*>(bk + part * BKPLANE + site * 20 + t4 * 4) = acc;
}

// ---------------------------------------------------------------------------
// Kernel 3: block = 8 consecutive sites, 256 threads, grid 2048.
// si = tid&7, cg = tid>>3; thread owns channels c = cg*2+k.
// Bk partial-sum over 160 threads; softmax by 8 threads; xbar -> R -> out.
// ---------------------------------------------------------------------------
template<int NPART>
__global__ __launch_bounds__(256) void ct_attn_out(
        const float* __restrict__ x,
        const float* __restrict__ w1,
        const float* __restrict__ b1,
        const float* __restrict__ bk,
        float* __restrict__ out) {
    __shared__ float w1t[64 * 65];   // w1t[cp*65 + c] = w1v[c][cp]
    __shared__ float psm[8][20];
    __shared__ float xsh[8][65];
    int tid = threadIdx.x;
    #pragma unroll
    for (int k = 0; k < 16; ++k) {
        int j = tid + k * 256;
        int r = j >> 6, q = j & 63;
        w1t[q * 65 + r] = w1[8192 + j];
    }

    int site0 = blockIdx.x * 8;

    if (tid < 160) {
        int si = tid / 20, i = tid % 20;
        float v = 0.f;
        #pragma unroll
        for (int pt = 0; pt < NPART; ++pt)
            v += bk[pt * BKPLANE + (site0 + si) * 20 + i];
        psm[si][i] = v;
    }
    __syncthreads();

    if (tid < 8) {
        float p[20];
        #pragma unroll
        for (int i = 0; i < 20; ++i) p[i] = psm[tid][i];
        float m = p[0];
        #pragma unroll
        for (int i = 1; i < 20; ++i) m = fmaxf(m, p[i]);
        float ssum = 0.f;
        #pragma unroll
        for (int i = 0; i < 20; ++i) { p[i] = __expf(p[i] - m); ssum += p[i]; }
        float inv = 1.f / ssum;
        #pragma unroll
        for (int i = 0; i < 20; ++i) psm[tid][i] = p[i] * inv;
    }
    __syncthreads();

    int si = tid & 7, cg = tid >> 3;
    int site = site0 + si;
    int b = site >> 12, hw = site & 4095;

    #pragma unroll
    for (int k = 0; k < 2; ++k) {
        int c = cg * 2 + k;
        const float* xp = x + (b * 64 + c) * XC + hw * 20;
        float xbv = 0.f;
        #pragma unroll
        for (int i = 0; i < 5; ++i) {
            float4 xv = reinterpret_cast<const float4*>(xp)[i];
            xbv = fmaf(psm[si][4 * i],     xv.x, xbv);
            xbv = fmaf(psm[si][4 * i + 1], xv.y, xbv);
            xbv = fmaf(psm[si][4 * i + 2], xv.z, xbv);
            xbv = fmaf(psm[si][4 * i + 3], xv.w, xbv);
        }
        xsh[si][c] = xbv;
    }
    __syncthreads();

    #pragma unroll
    for (int k = 0; k < 2; ++k) {
        int c = cg * 2 + k;
        float R = b1[128 + c];
        #pragma unroll 8
        for (int cp = 0; cp < 64; ++cp)
            R = fmaf(w1t[cp * 65 + c], xsh[si][cp], R);
        float* op = out + (b * 64 + c) * XC + hw * 20;
        float4 rv = make_float4(R, R, R, R);
        #pragma unroll
        for (int s4 = 0; s4 < 5; ++s4)
            reinterpret_cast<float4*>(op)[s4] = rv;
    }
}

extern "C" void kernel_launch(void* const* d_in, const int* in_sizes, int n_in,
                              void* d_out, int out_size, void* d_ws, size_t ws_size,
                              hipStream_t stream) {
    const float* x  = (const float*)d_in[0];
    const float* w1 = (const float*)d_in[1];
    const float* b1 = (const float*)d_in[2];
    const float* w2 = (const float*)d_in[3];
    // d_in[4] (b2) is mathematically dead: it cancels in the softmax over t.
    float* ws    = (float*)d_ws;
    float* bkbuf = ws + 640;
    float* out   = (float*)d_out;

    ct_fold_weights<<<1, 640, 0, stream>>>(w1, b1, w2, ws);

    size_t need16 = (size_t)(640 + 16 * BKPLANE) * sizeof(float);
    size_t need8  = (size_t)(640 + 8 * BKPLANE) * sizeof(float);
    size_t need4  = (size_t)(640 + 4 * BKPLANE) * sizeof(float);
    if (ws_size >= need16) {
        // NCP=4 -> NPART=16, grid = 4*16*16 = 1024
        ct_conv_scatter<4><<<1024, 320, 0, stream>>>(x, ws, bkbuf);
        ct_attn_out<16><<<2048, 256, 0, stream>>>(x, w1, b1, bkbuf, out);
    } else if (ws_size >= need8) {
        // NCP=8 -> NPART=8, grid = 4*8*16 = 512
        ct_conv_scatter<8><<<512, 320, 0, stream>>>(x, ws, bkbuf);
        ct_attn_out<8><<<2048, 256, 0, stream>>>(x, w1, b1, bkbuf, out);
    } else if (ws_size >= need4) {
        ct_conv_bk<4><<<1024, 320, 0, stream>>>(x, ws, bkbuf);
        ct_attn_out<4><<<2048, 256, 0, stream>>>(x, w1, b1, bkbuf, out);
    } else {
        ct_conv_bk<1><<<256, 320, 0, stream>>>(x, ws, bkbuf);
        ct_attn_out<1><<<2048, 256, 0, stream>>>(x, w1, b1, bkbuf, out);
    }
}